// Round 12
// baseline (286.460 us; speedup 1.0000x reference)
//
#include <hip/hip_runtime.h>
#include <hip/hip_bf16.h>

// SelfOtherAwareAttention: B=4, L=S=2048, D=256, H=8, hd=32
// qp/kp in workspace: [B*2048][512] bf16, cols 0:256 = self-proj, 256:512 = other-proj
// scale (hd^-0.5) folded into qp.
// R12: write-window compaction. Tile = (b,h,lt,sc) -> 16384 blocks, 1D grid ordered
// sc->lt->h->b so co-resident blocks write ONE contiguous 16MB out[b][h] slab
// (fill-like DRAM frontier). mask/som re-read per h is served by L3 (32MB hot set
// per b); stores are NT so the write stream doesn't evict it.

typedef __attribute__((ext_vector_type(8))) __bf16 bf16x8;
typedef __attribute__((ext_vector_type(4))) float f32x4;
typedef __attribute__((ext_vector_type(4))) int i32x4;
typedef __attribute__((ext_vector_type(4))) unsigned int u32x4;

#define MFMA16(a, b, c) __builtin_amdgcn_mfma_f32_16x16x32_bf16((a), (b), (c), 0, 0, 0)

__device__ __forceinline__ bf16x8 load8_f32_to_bf16(const float* __restrict__ p) {
    float4 f0 = *(const float4*)p;
    float4 f1 = *(const float4*)(p + 4);
    bf16x8 r;
    r[0] = (__bf16)f0.x; r[1] = (__bf16)f0.y; r[2] = (__bf16)f0.z; r[3] = (__bf16)f0.w;
    r[4] = (__bf16)f1.x; r[5] = (__bf16)f1.y; r[6] = (__bf16)f1.z; r[7] = (__bf16)f1.w;
    return r;
}

// ---------------- Fused projections: q-side and k-side in one dispatch ----------------
__global__ __launch_bounds__(256) void proj_kernel(
    const float* __restrict__ qin, const float* __restrict__ kin,
    const float* __restrict__ Wqs, const float* __restrict__ Wqo,
    const float* __restrict__ Wks, const float* __restrict__ Wko,
    __bf16* __restrict__ qout, __bf16* __restrict__ kout)
{
    const bool isK = blockIdx.y >= 64;
    const float* in = isK ? kin : qin;
    const float* Ws = isK ? Wks : Wqs;
    const float* Wo = isK ? Wko : Wqo;
    __bf16* outp    = isK ? kout : qout;
    const float scale = isK ? 1.0f : 0.17677669529663687f;  // 32^-0.5

    const int n0 = blockIdx.x * 64;
    const int m0 = (blockIdx.y & 63) * 128;
    const int tid  = threadIdx.x;
    const int lane = tid & 63;
    const int w    = tid >> 6;
    const int wr = w >> 1, wc = w & 1;
    const int l15 = lane & 15, l4 = lane >> 4;

    f32x4 acc[4][2];
#pragma unroll
    for (int mi = 0; mi < 4; ++mi)
#pragma unroll
        for (int ni = 0; ni < 2; ++ni) acc[mi][ni] = (f32x4){0.f, 0.f, 0.f, 0.f};

    const int arow0 = m0 + wr * 64 + l15;  // + mi*16

    const float* wptr[2];
#pragma unroll
    for (int ni = 0; ni < 2; ++ni) {
        int c = n0 + wc * 32 + ni * 16 + l15;
        wptr[ni] = (c < 256) ? (Ws + c * 256) : (Wo + (c - 256) * 256);
    }

#pragma unroll
    for (int ks = 0; ks < 8; ++ks) {
        const int k0 = ks * 32 + l4 * 8;
        bf16x8 a[4], b[2];
#pragma unroll
        for (int mi = 0; mi < 4; ++mi)
            a[mi] = load8_f32_to_bf16(in + (arow0 + mi * 16) * 256 + k0);
#pragma unroll
        for (int ni = 0; ni < 2; ++ni)
            b[ni] = load8_f32_to_bf16(wptr[ni] + k0);
#pragma unroll
        for (int mi = 0; mi < 4; ++mi)
#pragma unroll
            for (int ni = 0; ni < 2; ++ni)
                acc[mi][ni] = MFMA16(a[mi], b[ni], acc[mi][ni]);
    }

    // C/D layout: col = lane&15, row = (lane>>4)*4 + j
#pragma unroll
    for (int mi = 0; mi < 4; ++mi)
#pragma unroll
        for (int ni = 0; ni < 2; ++ni)
#pragma unroll
            for (int j = 0; j < 4; ++j) {
                int row = m0 + wr * 64 + mi * 16 + l4 * 4 + j;
                int col = n0 + wc * 32 + ni * 16 + l15;
                outp[row * 512 + col] = (__bf16)(acc[mi][ni][j] * scale);
            }
}

// ---------------- Fused attention (h-split tiles, compact write window) ----------------
// 1D grid 16384: x -> sc = x&7, lt = (x>>3)&63, h = (x>>9)&7, b = x>>12.
// Consecutive block IDs sweep sc then lt within one (b,h) slab (512 blocks = the
// whole 16MB out[b][h]); HW dispatches ~in ID order -> the chip-wide write frontier
// is a compact sliding window. Within one b, the 8 h-slabs reuse that b's 32MB
// mask+som hot set via L3 (plain loads allocate; HBM fetches it once).
// Block = 4 waves; wave w owns 32l x 64s at s-offset w*64 of the 32x256 tile.
// mfma(A=k_frag, B=q_frag): D col=lane&15 -> l, row=(lane>>4)*4+j -> s.
// Epilogue: compute -> LDS [32][260] -> 1KB-contiguous NT row-stores; block exits
// (stores drain at wave exit, overlapped with next blocks).
__global__ __launch_bounds__(256) void attn_kernel(
    const __bf16* __restrict__ qp, const __bf16* __restrict__ kp,
    const int* __restrict__ som, const float* __restrict__ mask,
    float* __restrict__ out)
{
    __shared__ float tile[32][260];

    const int x  = blockIdx.x;
    const int sc = x & 7;
    const int lt = (x >> 3) & 63;
    const int h  = (x >> 9) & 7;
    const int b  = x >> 12;

    const int s0 = sc * 256;
    const int l0 = lt * 32;
    const int tid  = threadIdx.x;
    const int lane = tid & 63;
    const int w    = tid >> 6;
    const int l15 = lane & 15, l4 = lane >> 4;

    // compute-layout coords (block-local): row = l15 + mi*16, col = w*64 + l4*4 + ni*16
    const int c_row = l15;
    const int c_col = w * 64 + l4 * 4;
    const int hofs  = h * 32;

    // fragment loads issued first (used after staging barriers)
    bf16x8 qb[2][2], ka[4][2];
#pragma unroll
    for (int mi = 0; mi < 2; ++mi)
#pragma unroll
        for (int p = 0; p < 2; ++p)
            qb[mi][p] = *(const bf16x8*)(qp + (long)(b * 2048 + l0 + l15 + mi * 16) * 512
                                            + p * 256 + hofs + l4 * 8);
#pragma unroll
    for (int ni = 0; ni < 4; ++ni)
#pragma unroll
        for (int p = 0; p < 2; ++p)
            ka[ni][p] = *(const bf16x8*)(kp + (long)(b * 2048 + s0 + w * 64 + l15 + ni * 16) * 512
                                            + p * 256 + hofs + l4 * 8);

    // ---- stage packed (mask | som-bit) through LDS: 1KB-coalesced PLAIN reads ----
    // (plain so lines allocate in L2/L3 for reuse by the other 7 h-slabs of this b)
#pragma unroll
    for (int i = 0; i < 8; ++i) {
        int r = i * 4 + w;
        long gidx = (long)(b * 2048 + l0 + r) * 2048 + s0 + 4 * lane;
        f32x4 m  = *(const f32x4*)(mask + gidx);
        i32x4 sm = *(const i32x4*)(som + gidx);
        u32x4 pk;
#pragma unroll
        for (int j = 0; j < 4; ++j)
            pk[j] = (__float_as_uint(m[j]) & ~1u) | (sm[j] != 0 ? 1u : 0u);
        *(u32x4*)&tile[r][4 * lane] = pk;
    }
    __syncthreads();

    f32x4 mreg[2][4];
    unsigned int sbits = 0;
#pragma unroll
    for (int mi = 0; mi < 2; ++mi)
#pragma unroll
        for (int ni = 0; ni < 4; ++ni) {
            u32x4 pk = *(const u32x4*)&tile[c_row + mi * 16][c_col + ni * 16];
            const int t0 = (mi * 4 + ni) * 4;
#pragma unroll
            for (int j = 0; j < 4; ++j) {
                sbits |= (pk[j] & 1u) << (t0 + j);
                mreg[mi][ni][j] = __uint_as_float(pk[j] & ~1u);
            }
        }
    __syncthreads();

    // ---- compute -> LDS (compute layout) ----
#pragma unroll
    for (int mi = 0; mi < 2; ++mi)
#pragma unroll
        for (int ni = 0; ni < 4; ++ni) {
            f32x4 z = (f32x4){0.f, 0.f, 0.f, 0.f};
            f32x4 as = MFMA16(ka[ni][0], qb[mi][0], z);   // self
            f32x4 ao = MFMA16(ka[ni][1], qb[mi][1], z);   // other
            const int t0 = (mi * 4 + ni) * 4;
            f32x4 v;
#pragma unroll
            for (int j = 0; j < 4; ++j)
                v[j] = (((sbits >> (t0 + j)) & 1u) ? as[j] : ao[j]) + mreg[mi][ni][j];
            *(f32x4*)&tile[c_row + mi * 16][c_col + ni * 16] = v;
        }
    __syncthreads();

    // ---- store: 1KB-contiguous NT row-slices; block exits, stores drain async ----
    const long obase = (long)((b * 8 + h) * 2048 + l0) * 2048 + s0;
#pragma unroll
    for (int i = 0; i < 8; ++i) {
        int r = i * 4 + w;
        f32x4 v = *(const f32x4*)&tile[r][4 * lane];
        __builtin_nontemporal_store(v, (f32x4*)(out + obase + (long)r * 2048 + 4 * lane));
    }
}

extern "C" void kernel_launch(void* const* d_in, const int* in_sizes, int n_in,
                              void* d_out, int out_size, void* d_ws, size_t ws_size,
                              hipStream_t stream) {
    const float* q    = (const float*)d_in[0];
    const float* k    = (const float*)d_in[1];
    const int*   som  = (const int*)d_in[2];
    const float* mask = (const float*)d_in[3];
    const float* Wqs  = (const float*)d_in[4];
    const float* Wqo  = (const float*)d_in[5];
    const float* Wks  = (const float*)d_in[6];
    const float* Wko  = (const float*)d_in[7];
    float* out = (float*)d_out;

    __bf16* qp = (__bf16*)d_ws;            // [8192][512]
    __bf16* kp = qp + 8192 * 512;          // [8192][512]

    dim3 pgrid(8, 128, 1), pblk(256, 1, 1);
    hipLaunchKernelGGL(proj_kernel, pgrid, pblk, 0, stream,
                       q, k, Wqs, Wqo, Wks, Wko, qp, kp);

    dim3 agrid(16384, 1, 1), ablk(256, 1, 1);
    hipLaunchKernelGGL(attn_kernel, agrid, ablk, 0, stream, qp, kp, som, mask, out);
}

// Round 13
// 195.954 us; speedup vs baseline: 1.4619x; 1.4619x over previous
//
#include <hip/hip_runtime.h>
#include <hip/hip_bf16.h>

// SelfOtherAwareAttention: B=4, L=S=2048, D=256, H=8, hd=32
// qp/kp in workspace: [B*2048][512] bf16, cols 0:256 = self-proj, 256:512 = other-proj
// scale (hd^-0.5) folded into qp.
// R13 = R10 frame with 32l x 512s tiles (8-wave blocks): output stores become 2KB
// runs via wave-pairing. Single change vs R10; mask/som still read exactly once.

typedef __attribute__((ext_vector_type(8))) __bf16 bf16x8;
typedef __attribute__((ext_vector_type(4))) float f32x4;
typedef __attribute__((ext_vector_type(4))) int i32x4;

#define MFMA16(a, b, c) __builtin_amdgcn_mfma_f32_16x16x32_bf16((a), (b), (c), 0, 0, 0)

__device__ __forceinline__ bf16x8 load8_f32_to_bf16(const float* __restrict__ p) {
    float4 f0 = *(const float4*)p;
    float4 f1 = *(const float4*)(p + 4);
    bf16x8 r;
    r[0] = (__bf16)f0.x; r[1] = (__bf16)f0.y; r[2] = (__bf16)f0.z; r[3] = (__bf16)f0.w;
    r[4] = (__bf16)f1.x; r[5] = (__bf16)f1.y; r[6] = (__bf16)f1.z; r[7] = (__bf16)f1.w;
    return r;
}

// ---------------- Fused projections: q-side and k-side in one dispatch ----------------
__global__ __launch_bounds__(256) void proj_kernel(
    const float* __restrict__ qin, const float* __restrict__ kin,
    const float* __restrict__ Wqs, const float* __restrict__ Wqo,
    const float* __restrict__ Wks, const float* __restrict__ Wko,
    __bf16* __restrict__ qout, __bf16* __restrict__ kout)
{
    const bool isK = blockIdx.y >= 64;
    const float* in = isK ? kin : qin;
    const float* Ws = isK ? Wks : Wqs;
    const float* Wo = isK ? Wko : Wqo;
    __bf16* outp    = isK ? kout : qout;
    const float scale = isK ? 1.0f : 0.17677669529663687f;  // 32^-0.5

    const int n0 = blockIdx.x * 64;
    const int m0 = (blockIdx.y & 63) * 128;
    const int tid  = threadIdx.x;
    const int lane = tid & 63;
    const int w    = tid >> 6;
    const int wr = w >> 1, wc = w & 1;
    const int l15 = lane & 15, l4 = lane >> 4;

    f32x4 acc[4][2];
#pragma unroll
    for (int mi = 0; mi < 4; ++mi)
#pragma unroll
        for (int ni = 0; ni < 2; ++ni) acc[mi][ni] = (f32x4){0.f, 0.f, 0.f, 0.f};

    const int arow0 = m0 + wr * 64 + l15;  // + mi*16

    const float* wptr[2];
#pragma unroll
    for (int ni = 0; ni < 2; ++ni) {
        int c = n0 + wc * 32 + ni * 16 + l15;
        wptr[ni] = (c < 256) ? (Ws + c * 256) : (Wo + (c - 256) * 256);
    }

#pragma unroll
    for (int ks = 0; ks < 8; ++ks) {
        const int k0 = ks * 32 + l4 * 8;
        bf16x8 a[4], b[2];
#pragma unroll
        for (int mi = 0; mi < 4; ++mi)
            a[mi] = load8_f32_to_bf16(in + (arow0 + mi * 16) * 256 + k0);
#pragma unroll
        for (int ni = 0; ni < 2; ++ni)
            b[ni] = load8_f32_to_bf16(wptr[ni] + k0);
#pragma unroll
        for (int mi = 0; mi < 4; ++mi)
#pragma unroll
            for (int ni = 0; ni < 2; ++ni)
                acc[mi][ni] = MFMA16(a[mi], b[ni], acc[mi][ni]);
    }

    // C/D layout: col = lane&15, row = (lane>>4)*4 + j
#pragma unroll
    for (int mi = 0; mi < 4; ++mi)
#pragma unroll
        for (int ni = 0; ni < 2; ++ni)
#pragma unroll
            for (int j = 0; j < 4; ++j) {
                int row = m0 + wr * 64 + mi * 16 + l4 * 4 + j;
                int col = n0 + wc * 32 + ni * 16 + l15;
                outp[row * 512 + col] = (__bf16)(acc[mi][ni][j] * scale);
            }
}

// ---------------- Fused attention (wide-row tile: 32l x 512s, 8 waves) ----------------
// grid (S/512=4, L/32=64, B=4), block 512 = 8 waves; wave w owns 32l x 64s at
// s-offset w*64 (identical per-wave geometry to R10).
// mfma(A=k_frag, B=q_frag): D col=lane&15 -> l, row=(lane>>4)*4+j -> s.
// Epilogue per h: compute -> LDS [32][516] -> paired-wave NT stores: waves (2q,2q+1)
// write the two 1KB halves of row r simultaneously -> 2KB contiguous runs.
// Mask/som staged once through the same LDS with 2KB-coalesced NT reads.
__global__ __launch_bounds__(512) void attn_kernel(
    const __bf16* __restrict__ qp, const __bf16* __restrict__ kp,
    const int* __restrict__ som, const float* __restrict__ mask,
    float* __restrict__ out)
{
    __shared__ float tile[32][516];   // stride 516 (516%32=4): all phases conflict-light

    const int s0 = blockIdx.x * 512;
    const int l0 = blockIdx.y * 32;
    const int b  = blockIdx.z;
    const int tid  = threadIdx.x;
    const int lane = tid & 63;
    const int w    = tid >> 6;
    const int l15 = lane & 15, l4 = lane >> 4;

    // compute-layout coords (block-local): row = l15 + mi*16, col = w*64 + l4*4 + ni*16
    const int c_row = l15;
    const int c_col = w * 64 + l4 * 4;

    // staging coords: 512 thr x f32x4 = 8KB/sweep = 4 rows; paired waves cover one
    // 2KB row: r = (tid>>7) + i*4, col = (tid&127)*4
    const int st_r = tid >> 7;
    const int st_c = (tid & 127) * 4;

    // ---- stage mask, then som, through LDS: coalesced 2KB reads -> compute-layout regs ----
    f32x4 mreg[2][4];
    unsigned int sbits = 0;
#pragma unroll
    for (int i = 0; i < 8; ++i) {
        int r = i * 4 + st_r;
        f32x4 m = __builtin_nontemporal_load(
            (const f32x4*)(mask + (long)(b * 2048 + l0 + r) * 2048 + s0 + st_c));
        *(f32x4*)&tile[r][st_c] = m;
    }
    __syncthreads();
#pragma unroll
    for (int mi = 0; mi < 2; ++mi)
#pragma unroll
        for (int ni = 0; ni < 4; ++ni)
            mreg[mi][ni] = *(const f32x4*)&tile[c_row + mi * 16][c_col + ni * 16];
    __syncthreads();
#pragma unroll
    for (int i = 0; i < 8; ++i) {
        int r = i * 4 + st_r;
        i32x4 sm = __builtin_nontemporal_load(
            (const i32x4*)(som + (long)(b * 2048 + l0 + r) * 2048 + s0 + st_c));
        *(i32x4*)&tile[r][st_c] = sm;
    }
    __syncthreads();
#pragma unroll
    for (int mi = 0; mi < 2; ++mi)
#pragma unroll
        for (int ni = 0; ni < 4; ++ni) {
            i32x4 sm = *(const i32x4*)&tile[c_row + mi * 16][c_col + ni * 16];
            const int t0 = (mi * 4 + ni) * 4;
#pragma unroll
            for (int j = 0; j < 4; ++j)
                sbits |= (sm[j] != 0) ? (1u << (t0 + j)) : 0u;
        }
    __syncthreads();

    // fragment bases: q rows = l (l0 + l15 + mi*16), k rows = s (s0 + w*64 + l15 + ni*16)
    const __bf16* qbase = qp + (long)(b * 2048 + l0 + l15) * 512 + l4 * 8;
    const __bf16* kbase = kp + (long)(b * 2048 + s0 + w * 64 + l15) * 512 + l4 * 8;

    // store coords: paired waves write row halves: r = i*4 + (w>>1), half = w&1
    const int out_half = (w & 1) * 256 + lane * 4;

    for (int h = 0; h < 8; ++h) {
        const int hofs = h * 32;
        bf16x8 qb[2][2], ka[4][2];
#pragma unroll
        for (int mi = 0; mi < 2; ++mi)
#pragma unroll
            for (int p = 0; p < 2; ++p)
                qb[mi][p] = *(const bf16x8*)(qbase + mi * 16 * 512 + p * 256 + hofs);
#pragma unroll
        for (int ni = 0; ni < 4; ++ni)
#pragma unroll
            for (int p = 0; p < 2; ++p)
                ka[ni][p] = *(const bf16x8*)(kbase + ni * 16 * 512 + p * 256 + hofs);

        // compute -> LDS (compute layout)
#pragma unroll
        for (int mi = 0; mi < 2; ++mi)
#pragma unroll
            for (int ni = 0; ni < 4; ++ni) {
                f32x4 z = (f32x4){0.f, 0.f, 0.f, 0.f};
                f32x4 as = MFMA16(ka[ni][0], qb[mi][0], z);   // self
                f32x4 ao = MFMA16(ka[ni][1], qb[mi][1], z);   // other
                const int t0 = (mi * 4 + ni) * 4;
                f32x4 v;
#pragma unroll
                for (int j = 0; j < 4; ++j)
                    v[j] = (((sbits >> (t0 + j)) & 1u) ? as[j] : ao[j]) + mreg[mi][ni][j];
                *(f32x4*)&tile[c_row + mi * 16][c_col + ni * 16] = v;
            }

        __syncthreads();

        // store: paired waves emit one 2KB contiguous run per row (NT)
        const long obase = (long)((b * 8 + h) * 2048 + l0) * 2048 + s0;
#pragma unroll
        for (int i = 0; i < 8; ++i) {
            int r = i * 4 + (w >> 1);
            f32x4 v = *(const f32x4*)&tile[r][out_half];
            __builtin_nontemporal_store(v, (f32x4*)(out + obase + (long)r * 2048 + out_half));
        }

        __syncthreads();
    }
}

extern "C" void kernel_launch(void* const* d_in, const int* in_sizes, int n_in,
                              void* d_out, int out_size, void* d_ws, size_t ws_size,
                              hipStream_t stream) {
    const float* q    = (const float*)d_in[0];
    const float* k    = (const float*)d_in[1];
    const int*   som  = (const int*)d_in[2];
    const float* mask = (const float*)d_in[3];
    const float* Wqs  = (const float*)d_in[4];
    const float* Wqo  = (const float*)d_in[5];
    const float* Wks  = (const float*)d_in[6];
    const float* Wko  = (const float*)d_in[7];
    float* out = (float*)d_out;

    __bf16* qp = (__bf16*)d_ws;            // [8192][512]
    __bf16* kp = qp + 8192 * 512;          // [8192][512]

    dim3 pgrid(8, 128, 1), pblk(256, 1, 1);
    hipLaunchKernelGGL(proj_kernel, pgrid, pblk, 0, stream,
                       q, k, Wqs, Wqo, Wks, Wko, qp, kp);

    dim3 agrid(4, 64, 4), ablk(512, 1, 1);
    hipLaunchKernelGGL(attn_kernel, agrid, ablk, 0, stream, qp, kp, som, mask, out);
}